// Round 5
// baseline (220.488 us; speedup 1.0000x reference)
//
#include <hip/hip_runtime.h>

constexpr int SG = 14;
constexpr int NCELL = 4096 * SG * SG;   // 802816

__device__ __forceinline__ float iou_xyxy(
    float ax0, float ay0, float ax1, float ay1,
    float bx0, float by0, float bx1, float by1)
{
    float ltx = fmaxf(ax0, bx0), lty = fmaxf(ay0, by0);
    float rbx = fminf(ax1, bx1), rby = fminf(ay1, by1);
    float w = fmaxf(rbx - ltx, 0.0f), h = fmaxf(rby - lty, 0.0f);
    float inter = w * h;
    float aa = (ax1 - ax0) * (ay1 - ay0);
    float ab = (bx1 - bx0) * (by1 - by0);
    return inter / (aa + ab - inter);
}

__global__ __launch_bounds__(256) void yolo_loss_kernel(
    const float* __restrict__ pred,          // [N,S,S,30]
    const float* __restrict__ tb,            // [N,S,S,4]
    const float* __restrict__ tc,            // [N,S,S,20]
    const unsigned char* __restrict__ mraw,  // bool (u8) or int32 — detected
    float* __restrict__ out)                 // 5 floats
{
    // --- detect mask dtype: int32 {0,1} has zero bytes at offsets %4 != 0 ---
    __shared__ int s_u8;
    if (threadIdx.x == 0) {
        unsigned a = 0;
        for (int i = 0; i < 256; ++i) if (i & 3) a |= mraw[i];
        s_u8 = (a != 0);
    }
    __syncthreads();
    const bool u8 = (s_u8 != 0);

    float reg = 0.0f, cont = 0.0f, noobj = 0.0f, cls = 0.0f;

    int cell = blockIdx.x * 256 + threadIdx.x;
    if (cell < NCELL) {
        float p[30];
        {
            const float2* pp = reinterpret_cast<const float2*>(pred + (size_t)cell * 30);
            #pragma unroll
            for (int k = 0; k < 15; ++k) { float2 v = pp[k]; p[2*k] = v.x; p[2*k+1] = v.y; }
        }
        const float4 t4 = reinterpret_cast<const float4*>(tb)[cell];
        float c[20];
        {
            const float2* cp = reinterpret_cast<const float2*>(tc + (size_t)cell * 20);
            #pragma unroll
            for (int k = 0; k < 10; ++k) { float2 v = cp[k]; c[2*k] = v.x; c[2*k+1] = v.y; }
        }
        const float m = u8 ? (mraw[cell] ? 1.0f : 0.0f)
                           : (reinterpret_cast<const int*>(mraw)[cell] ? 1.0f : 0.0f);

        // classification loss
        float clsv = 0.0f;
        #pragma unroll
        for (int k = 0; k < 20; ++k) { float d = p[10 + k] - c[k]; clsv = fmaf(d, d, clsv); }
        cls = m * clsv;

        // no-object confidence loss
        noobj = (1.0f - m) * (p[4] * p[4] + p[9] * p[9]);

        // boxes -> xyxy
        const float invS = 1.0f / 14.0f;
        float tx0 = t4.x * invS - 0.5f * t4.z, ty0 = t4.y * invS - 0.5f * t4.w;
        float tx1 = t4.x * invS + 0.5f * t4.z, ty1 = t4.y * invS + 0.5f * t4.w;

        float a1x0 = p[0] * invS - 0.5f * p[2], a1y0 = p[1] * invS - 0.5f * p[3];
        float a1x1 = p[0] * invS + 0.5f * p[2], a1y1 = p[1] * invS + 0.5f * p[3];
        float a2x0 = p[5] * invS - 0.5f * p[7], a2y0 = p[6] * invS - 0.5f * p[8];
        float a2x1 = p[5] * invS + 0.5f * p[7], a2y1 = p[6] * invS + 0.5f * p[8];

        float iou1 = iou_xyxy(tx0, ty0, tx1, ty1, a1x0, a1y0, a1x1, a1y1);
        float iou2 = iou_xyxy(tx0, ty0, tx1, ty1, a2x0, a2y0, a2x1, a2y1);

        bool  use1 = iou1 > iou2;
        float biou = use1 ? iou1 : iou2;
        float bx = use1 ? p[0] : p[5];
        float by = use1 ? p[1] : p[6];
        float bw = use1 ? p[2] : p[7];
        float bh = use1 ? p[3] : p[8];
        float bc = use1 ? p[4] : p[9];

        float dx = bx - t4.x, dy = by - t4.y;
        float sw = sqrtf(bw) - sqrtf(t4.z);
        float sh = sqrtf(bh) - sqrtf(t4.w);
        reg  = m * (dx * dx + dy * dy + sw * sw + sh * sh);
        float dc = bc - biou;
        cont = m * dc * dc;
    }

    // --- wave (64-lane) reduction ---
    #pragma unroll
    for (int off = 32; off > 0; off >>= 1) {
        reg   += __shfl_down(reg,   off);
        cont  += __shfl_down(cont,  off);
        noobj += __shfl_down(noobj, off);
        cls   += __shfl_down(cls,   off);
    }

    __shared__ float sred[4][4];
    const int wid  = threadIdx.x >> 6;
    const int lane = threadIdx.x & 63;
    if (lane == 0) {
        sred[wid][0] = reg; sred[wid][1] = cont;
        sred[wid][2] = noobj; sred[wid][3] = cls;
    }
    __syncthreads();
    if (threadIdx.x == 0) {
        float r = 0, co = 0, no = 0, cl = 0;
        for (int w = 0; w < 4; ++w) {
            r += sred[w][0]; co += sred[w][1]; no += sred[w][2]; cl += sred[w][3];
        }
        atomicAdd(&out[0], 5.0f * r + co + 0.5f * no + cl);
        atomicAdd(&out[1], r);
        atomicAdd(&out[2], co);
        atomicAdd(&out[3], no);
        atomicAdd(&out[4], cl);
    }
}

extern "C" void kernel_launch(void* const* d_in, const int* in_sizes, int n_in,
                              void* d_out, int out_size, void* d_ws, size_t ws_size,
                              hipStream_t stream) {
    const float* pred         = (const float*)d_in[0];
    const float* tboxes       = (const float*)d_in[1];
    const float* tcls         = (const float*)d_in[2];
    const unsigned char* mask = (const unsigned char*)d_in[3];
    float* out = (float*)d_out;

    hipMemsetAsync(out, 0, 5 * sizeof(float), stream);

    const int blocks = (NCELL + 255) / 256;   // 3136
    yolo_loss_kernel<<<blocks, 256, 0, stream>>>(pred, tboxes, tcls, mask, out);
}

// Round 6
// 217.774 us; speedup vs baseline: 1.0125x; 1.0125x over previous
//
#include <hip/hip_runtime.h>

constexpr int NCELL = 4096 * 14 * 14;    // 802816
constexpr int NBLK  = NCELL / 256;       // 3136 (exact)

__device__ __forceinline__ float iou_xyxy(
    float ax0, float ay0, float ax1, float ay1,
    float bx0, float by0, float bx1, float by1)
{
    float ltx = fmaxf(ax0, bx0), lty = fmaxf(ay0, by0);
    float rbx = fminf(ax1, bx1), rby = fminf(ay1, by1);
    float w = fmaxf(rbx - ltx, 0.0f), h = fmaxf(rby - lty, 0.0f);
    float inter = w * h;
    float aa = (ax1 - ax0) * (ay1 - ay0);
    float ab = (bx1 - bx0) * (by1 - by0);
    return inter / (aa + ab - inter);
}

__global__ __launch_bounds__(256) void yolo_loss_kernel(
    const float* __restrict__ pred,          // [N,S,S,30]
    const float* __restrict__ tb,            // [N,S,S,4]
    const float* __restrict__ tc,            // [N,S,S,20]
    const unsigned char* __restrict__ mraw,  // bool (u8) or int32 — detected
    float* __restrict__ out)                 // 5 floats
{
    __shared__ float4 spv[1920];   // 256 cells x 30 floats = 30720 B
    __shared__ float4 scv[1280];   // 256 cells x 20 floats = 20480 B
    __shared__ float  sred[4][4];
    __shared__ int    s_u8;

    const int tid  = threadIdx.x;
    const int base = blockIdx.x * 256;

    // ---- issue ALL global loads up front (independent, coalesced float4) ----
    const float4* gp = reinterpret_cast<const float4*>(pred + (size_t)base * 30);
    const float4* gc = reinterpret_cast<const float4*>(tc   + (size_t)base * 20);

    float4 rp0 = gp[tid];
    float4 rp1 = gp[tid + 256];
    float4 rp2 = gp[tid + 512];
    float4 rp3 = gp[tid + 768];
    float4 rp4 = gp[tid + 1024];
    float4 rp5 = gp[tid + 1280];
    float4 rp6 = gp[tid + 1536];
    float4 rp7 = make_float4(0.f, 0.f, 0.f, 0.f);
    if (tid < 128) rp7 = gp[tid + 1792];          // 1920 float4 total

    float4 rc0 = gc[tid];
    float4 rc1 = gc[tid + 256];
    float4 rc2 = gc[tid + 512];
    float4 rc3 = gc[tid + 768];
    float4 rc4 = gc[tid + 1024];

    const float4 t4 = reinterpret_cast<const float4*>(tb)[base + tid];

    const unsigned char m_u8 = mraw[base + tid];
    const int m_i32 = reinterpret_cast<const int*>(mraw)[base + tid];
    unsigned dw = 0;
    if (tid < 64) dw = reinterpret_cast<const unsigned*>(mraw)[tid];

    // ---- LDS stage ----
    spv[tid]        = rp0;
    spv[tid + 256]  = rp1;
    spv[tid + 512]  = rp2;
    spv[tid + 768]  = rp3;
    spv[tid + 1024] = rp4;
    spv[tid + 1280] = rp5;
    spv[tid + 1536] = rp6;
    if (tid < 128) spv[tid + 1792] = rp7;

    scv[tid]        = rc0;
    scv[tid + 256]  = rc1;
    scv[tid + 512]  = rc2;
    scv[tid + 768]  = rc3;
    scv[tid + 1024] = rc4;

    // mask dtype probe: int32 {0,1} has zero bytes at offsets %4 != 0.
    // wave 0 checks the first 64 words; random-u8 false-positive ~2^-192.
    if (tid < 64) {
        unsigned long long b = __ballot((dw & 0xFFFFFF00u) != 0u);
        if (tid == 0) s_u8 = (b != 0ULL);
    }
    __syncthreads();

    const float m = (s_u8 ? (m_u8 != 0) : (m_i32 != 0)) ? 1.0f : 0.0f;

    // ---- per-cell compute from LDS ----
    float p[30];
    {
        const float2* pp = reinterpret_cast<const float2*>(
            reinterpret_cast<const float*>(spv) + tid * 30);
        #pragma unroll
        for (int k = 0; k < 15; ++k) { float2 v = pp[k]; p[2*k] = v.x; p[2*k+1] = v.y; }
    }
    float c[20];
    {
        const float2* cp = reinterpret_cast<const float2*>(
            reinterpret_cast<const float*>(scv) + tid * 20);
        #pragma unroll
        for (int k = 0; k < 10; ++k) { float2 v = cp[k]; c[2*k] = v.x; c[2*k+1] = v.y; }
    }

    // classification loss
    float clsv = 0.0f;
    #pragma unroll
    for (int k = 0; k < 20; ++k) { float d = p[10 + k] - c[k]; clsv = fmaf(d, d, clsv); }
    float cls = m * clsv;

    // no-object confidence loss
    float noobj = (1.0f - m) * (p[4] * p[4] + p[9] * p[9]);

    // boxes -> xyxy
    const float invS = 1.0f / 14.0f;
    float tx0 = t4.x * invS - 0.5f * t4.z, ty0 = t4.y * invS - 0.5f * t4.w;
    float tx1 = t4.x * invS + 0.5f * t4.z, ty1 = t4.y * invS + 0.5f * t4.w;

    float a1x0 = p[0] * invS - 0.5f * p[2], a1y0 = p[1] * invS - 0.5f * p[3];
    float a1x1 = p[0] * invS + 0.5f * p[2], a1y1 = p[1] * invS + 0.5f * p[3];
    float a2x0 = p[5] * invS - 0.5f * p[7], a2y0 = p[6] * invS - 0.5f * p[8];
    float a2x1 = p[5] * invS + 0.5f * p[7], a2y1 = p[6] * invS + 0.5f * p[8];

    float iou1 = iou_xyxy(tx0, ty0, tx1, ty1, a1x0, a1y0, a1x1, a1y1);
    float iou2 = iou_xyxy(tx0, ty0, tx1, ty1, a2x0, a2y0, a2x1, a2y1);

    bool  use1 = iou1 > iou2;
    float biou = use1 ? iou1 : iou2;
    float bx = use1 ? p[0] : p[5];
    float by = use1 ? p[1] : p[6];
    float bw = use1 ? p[2] : p[7];
    float bh = use1 ? p[3] : p[8];
    float bc = use1 ? p[4] : p[9];

    float dx = bx - t4.x, dy = by - t4.y;
    float sw = sqrtf(bw) - sqrtf(t4.z);
    float sh = sqrtf(bh) - sqrtf(t4.w);
    float reg  = m * (dx * dx + dy * dy + sw * sw + sh * sh);
    float dc = bc - biou;
    float cont = m * dc * dc;

    // ---- wave (64-lane) reduction ----
    #pragma unroll
    for (int off = 32; off > 0; off >>= 1) {
        reg   += __shfl_down(reg,   off);
        cont  += __shfl_down(cont,  off);
        noobj += __shfl_down(noobj, off);
        cls   += __shfl_down(cls,   off);
    }

    const int wid  = tid >> 6;
    const int lane = tid & 63;
    if (lane == 0) {
        sred[wid][0] = reg; sred[wid][1] = cont;
        sred[wid][2] = noobj; sred[wid][3] = cls;
    }
    __syncthreads();
    if (tid == 0) {
        float r = 0, co = 0, no = 0, cl = 0;
        #pragma unroll
        for (int w = 0; w < 4; ++w) {
            r += sred[w][0]; co += sred[w][1]; no += sred[w][2]; cl += sred[w][3];
        }
        atomicAdd(&out[0], 5.0f * r + co + 0.5f * no + cl);
        atomicAdd(&out[1], r);
        atomicAdd(&out[2], co);
        atomicAdd(&out[3], no);
        atomicAdd(&out[4], cl);
    }
}

extern "C" void kernel_launch(void* const* d_in, const int* in_sizes, int n_in,
                              void* d_out, int out_size, void* d_ws, size_t ws_size,
                              hipStream_t stream) {
    const float* pred         = (const float*)d_in[0];
    const float* tboxes       = (const float*)d_in[1];
    const float* tcls         = (const float*)d_in[2];
    const unsigned char* mask = (const unsigned char*)d_in[3];
    float* out = (float*)d_out;

    hipMemsetAsync(out, 0, 5 * sizeof(float), stream);

    yolo_loss_kernel<<<NBLK, 256, 0, stream>>>(pred, tboxes, tcls, mask, out);
}

// Round 7
// 36.533 us; speedup vs baseline: 6.0354x; 5.9611x over previous
//
#include <hip/hip_runtime.h>

constexpr int NCELL = 4096 * 14 * 14;    // 802816
constexpr int NBLK  = NCELL / 256;       // 3136 (exact)

__device__ __forceinline__ float iou_xyxy(
    float ax0, float ay0, float ax1, float ay1,
    float bx0, float by0, float bx1, float by1)
{
    float ltx = fmaxf(ax0, bx0), lty = fmaxf(ay0, by0);
    float rbx = fminf(ax1, bx1), rby = fminf(ay1, by1);
    float w = fmaxf(rbx - ltx, 0.0f), h = fmaxf(rby - lty, 0.0f);
    float inter = w * h;
    float aa = (ax1 - ax0) * (ay1 - ay0);
    float ab = (bx1 - bx0) * (by1 - by0);
    return inter / (aa + ab - inter);
}

__global__ __launch_bounds__(256) void yolo_main(
    const float* __restrict__ pred,          // [N,S,S,30]
    const float* __restrict__ tb,            // [N,S,S,4]
    const float* __restrict__ tc,            // [N,S,S,20]
    const unsigned char* __restrict__ mraw,  // bool (u8) or int32 — detected
    float4* __restrict__ partials,           // [NBLK] (r,co,no,cl) or null
    float* __restrict__ out)
{
    __shared__ float4 spv[1920];   // 256 cells x 30 floats = 30720 B
    __shared__ float  sred[4][4];
    __shared__ int    s_u8;

    const int tid  = threadIdx.x;
    const int base = blockIdx.x * 256;

    // ---- pred: cooperative coalesced float4 loads (all independent) ----
    const float4* gp = reinterpret_cast<const float4*>(pred + (size_t)base * 30);
    float4 rp0 = gp[tid];
    float4 rp1 = gp[tid + 256];
    float4 rp2 = gp[tid + 512];
    float4 rp3 = gp[tid + 768];
    float4 rp4 = gp[tid + 1024];
    float4 rp5 = gp[tid + 1280];
    float4 rp6 = gp[tid + 1536];
    float4 rp7 = make_float4(0.f, 0.f, 0.f, 0.f);
    if (tid < 128) rp7 = gp[tid + 1792];          // 1920 float4 total

    // ---- tc: per-cell 80 B is 16-B aligned -> direct float4 loads ----
    const float4* gc = reinterpret_cast<const float4*>(tc + (size_t)(base + tid) * 20);
    float4 rc0 = gc[0], rc1 = gc[1], rc2 = gc[2], rc3 = gc[3], rc4 = gc[4];

    const float4 t4 = reinterpret_cast<const float4*>(tb)[base + tid];

    const unsigned char m_u8 = mraw[base + tid];
    const int m_i32 = reinterpret_cast<const int*>(mraw)[base + tid];
    unsigned dw = 0;
    if (tid < 64) dw = reinterpret_cast<const unsigned*>(mraw)[tid];

    // ---- LDS stage (pred only) ----
    spv[tid]        = rp0;
    spv[tid + 256]  = rp1;
    spv[tid + 512]  = rp2;
    spv[tid + 768]  = rp3;
    spv[tid + 1024] = rp4;
    spv[tid + 1280] = rp5;
    spv[tid + 1536] = rp6;
    if (tid < 128) spv[tid + 1792] = rp7;

    // mask dtype probe: int32 {0,1} has zero bytes at offsets %4 != 0
    if (tid < 64) {
        unsigned long long b = __ballot((dw & 0xFFFFFF00u) != 0u);
        if (tid == 0) s_u8 = (b != 0ULL);
    }
    __syncthreads();

    const float m = (s_u8 ? (m_u8 != 0) : (m_i32 != 0)) ? 1.0f : 0.0f;

    // ---- per-cell compute (pred from LDS, tc from registers) ----
    float p[30];
    {
        const float2* pp = reinterpret_cast<const float2*>(
            reinterpret_cast<const float*>(spv) + tid * 30);
        #pragma unroll
        for (int k = 0; k < 15; ++k) { float2 v = pp[k]; p[2*k] = v.x; p[2*k+1] = v.y; }
    }
    float c[20] = {rc0.x, rc0.y, rc0.z, rc0.w, rc1.x, rc1.y, rc1.z, rc1.w,
                   rc2.x, rc2.y, rc2.z, rc2.w, rc3.x, rc3.y, rc3.z, rc3.w,
                   rc4.x, rc4.y, rc4.z, rc4.w};

    float clsv = 0.0f;
    #pragma unroll
    for (int k = 0; k < 20; ++k) { float d = p[10 + k] - c[k]; clsv = fmaf(d, d, clsv); }
    float cls = m * clsv;

    float noobj = (1.0f - m) * (p[4] * p[4] + p[9] * p[9]);

    const float invS = 1.0f / 14.0f;
    float tx0 = t4.x * invS - 0.5f * t4.z, ty0 = t4.y * invS - 0.5f * t4.w;
    float tx1 = t4.x * invS + 0.5f * t4.z, ty1 = t4.y * invS + 0.5f * t4.w;

    float a1x0 = p[0] * invS - 0.5f * p[2], a1y0 = p[1] * invS - 0.5f * p[3];
    float a1x1 = p[0] * invS + 0.5f * p[2], a1y1 = p[1] * invS + 0.5f * p[3];
    float a2x0 = p[5] * invS - 0.5f * p[7], a2y0 = p[6] * invS - 0.5f * p[8];
    float a2x1 = p[5] * invS + 0.5f * p[7], a2y1 = p[6] * invS + 0.5f * p[8];

    float iou1 = iou_xyxy(tx0, ty0, tx1, ty1, a1x0, a1y0, a1x1, a1y1);
    float iou2 = iou_xyxy(tx0, ty0, tx1, ty1, a2x0, a2y0, a2x1, a2y1);

    bool  use1 = iou1 > iou2;
    float biou = use1 ? iou1 : iou2;
    float bx = use1 ? p[0] : p[5];
    float by = use1 ? p[1] : p[6];
    float bw = use1 ? p[2] : p[7];
    float bh = use1 ? p[3] : p[8];
    float bc = use1 ? p[4] : p[9];

    float dx = bx - t4.x, dy = by - t4.y;
    float sw = sqrtf(bw) - sqrtf(t4.z);
    float sh = sqrtf(bh) - sqrtf(t4.w);
    float reg  = m * (dx * dx + dy * dy + sw * sw + sh * sh);
    float dc = bc - biou;
    float cont = m * dc * dc;

    // ---- wave (64-lane) reduction ----
    #pragma unroll
    for (int off = 32; off > 0; off >>= 1) {
        reg   += __shfl_down(reg,   off);
        cont  += __shfl_down(cont,  off);
        noobj += __shfl_down(noobj, off);
        cls   += __shfl_down(cls,   off);
    }

    const int wid  = tid >> 6;
    const int lane = tid & 63;
    if (lane == 0) {
        sred[wid][0] = reg; sred[wid][1] = cont;
        sred[wid][2] = noobj; sred[wid][3] = cls;
    }
    __syncthreads();
    if (tid == 0) {
        float r = 0, co = 0, no = 0, cl = 0;
        #pragma unroll
        for (int w = 0; w < 4; ++w) {
            r += sred[w][0]; co += sred[w][1]; no += sred[w][2]; cl += sred[w][3];
        }
        if (partials) {
            partials[blockIdx.x] = make_float4(r, co, no, cl);
        } else {
            atomicAdd(&out[0], 5.0f * r + co + 0.5f * no + cl);
            atomicAdd(&out[1], r);
            atomicAdd(&out[2], co);
            atomicAdd(&out[3], no);
            atomicAdd(&out[4], cl);
        }
    }
}

__global__ __launch_bounds__(256) void yolo_reduce(
    const float4* __restrict__ partials, float* __restrict__ out)
{
    const int tid = threadIdx.x;
    float r = 0, co = 0, no = 0, cl = 0;
    for (int i = tid; i < NBLK; i += 256) {
        float4 v = partials[i];
        r += v.x; co += v.y; no += v.z; cl += v.w;
    }
    #pragma unroll
    for (int off = 32; off > 0; off >>= 1) {
        r  += __shfl_down(r,  off);
        co += __shfl_down(co, off);
        no += __shfl_down(no, off);
        cl += __shfl_down(cl, off);
    }
    __shared__ float sred[4][4];
    const int wid  = tid >> 6;
    const int lane = tid & 63;
    if (lane == 0) { sred[wid][0] = r; sred[wid][1] = co; sred[wid][2] = no; sred[wid][3] = cl; }
    __syncthreads();
    if (tid == 0) {
        float R = 0, CO = 0, NO = 0, CL = 0;
        #pragma unroll
        for (int w = 0; w < 4; ++w) {
            R += sred[w][0]; CO += sred[w][1]; NO += sred[w][2]; CL += sred[w][3];
        }
        out[0] = 5.0f * R + CO + 0.5f * NO + CL;
        out[1] = R;
        out[2] = CO;
        out[3] = NO;
        out[4] = CL;
    }
}

extern "C" void kernel_launch(void* const* d_in, const int* in_sizes, int n_in,
                              void* d_out, int out_size, void* d_ws, size_t ws_size,
                              hipStream_t stream) {
    const float* pred         = (const float*)d_in[0];
    const float* tboxes       = (const float*)d_in[1];
    const float* tcls         = (const float*)d_in[2];
    const unsigned char* mask = (const unsigned char*)d_in[3];
    float* out = (float*)d_out;

    const bool two_stage = (ws_size >= (size_t)NBLK * sizeof(float4));
    float4* partials = two_stage ? (float4*)d_ws : nullptr;

    if (!two_stage) hipMemsetAsync(out, 0, 5 * sizeof(float), stream);

    yolo_main<<<NBLK, 256, 0, stream>>>(pred, tboxes, tcls, mask, partials, out);
    if (two_stage) yolo_reduce<<<1, 256, 0, stream>>>(partials, out);
}

// Round 8
// 36.231 us; speedup vs baseline: 6.0855x; 1.0083x over previous
//
#include <hip/hip_runtime.h>

constexpr int NCELL = 4096 * 14 * 14;    // 802816
constexpr int NBLK  = NCELL / 256;       // 3136 (exact)

__device__ __forceinline__ float iou_xyxy(
    float ax0, float ay0, float ax1, float ay1,
    float bx0, float by0, float bx1, float by1)
{
    float ltx = fmaxf(ax0, bx0), lty = fmaxf(ay0, by0);
    float rbx = fminf(ax1, bx1), rby = fminf(ay1, by1);
    float w = fmaxf(rbx - ltx, 0.0f), h = fmaxf(rby - lty, 0.0f);
    float inter = w * h;
    float aa = (ax1 - ax0) * (ay1 - ay0);
    float ab = (bx1 - bx0) * (by1 - by0);
    return inter / (aa + ab - inter);
}

__global__ __launch_bounds__(256) void yolo_main(
    const float* __restrict__ pred,          // [N,S,S,30]
    const float* __restrict__ tb,            // [N,S,S,4]
    const float* __restrict__ tc,            // [N,S,S,20]
    const unsigned char* __restrict__ mraw,  // bool (u8) or int32 — detected
    float4* __restrict__ partials,           // [NBLK] (r,co,no,cl) or null
    float* __restrict__ out)
{
    // per-wave private LDS chunks: no block barrier needed for staging
    __shared__ float spv[4][1920];   // 4 waves x (64 cells x 30 floats) = 30720 B
    __shared__ float sred[4][4];

    const int tid   = threadIdx.x;
    const int lane  = tid & 63;
    const int wid   = tid >> 6;
    const int base  = blockIdx.x * 256;
    const int wbase = base + wid * 64;       // this wave's first cell

    // ---- pred: wave-cooperative coalesced float4 loads (480 f4 per wave) ----
    const float4* gpw = reinterpret_cast<const float4*>(pred + (size_t)wbase * 30);
    float4 r0 = gpw[lane];
    float4 r1 = gpw[lane + 64];
    float4 r2 = gpw[lane + 128];
    float4 r3 = gpw[lane + 192];
    float4 r4 = gpw[lane + 256];
    float4 r5 = gpw[lane + 320];
    float4 r6 = gpw[lane + 384];
    float4 r7 = make_float4(0.f, 0.f, 0.f, 0.f);
    if (lane < 32) r7 = gpw[lane + 448];     // 448 + 32 = 480

    // ---- tc: per-cell 80 B, 16-B aligned -> direct float4 loads ----
    const float4* gc = reinterpret_cast<const float4*>(tc + (size_t)(base + tid) * 20);
    float4 rc0 = gc[0], rc1 = gc[1], rc2 = gc[2], rc3 = gc[3], rc4 = gc[4];

    const float4 t4 = reinterpret_cast<const float4*>(tb)[base + tid];

    const unsigned char m_u8 = mraw[base + tid];
    const int m_i32 = reinterpret_cast<const int*>(mraw)[base + tid];

    // mask dtype probe, per-wave (barrier-free): int32 {0,1} data has zero
    // bytes at offsets %4 != 0 over the first 256 bytes; random-u8 FP ~2^-192.
    const unsigned dw = reinterpret_cast<const unsigned*>(mraw)[lane];
    const bool u8 = (__ballot((dw & 0xFFFFFF00u) != 0u) != 0ULL);

    // ---- stage pred into this wave's LDS slice (wave-synchronous) ----
    float4* swv = reinterpret_cast<float4*>(spv[wid]);
    swv[lane]        = r0;
    swv[lane + 64]   = r1;
    swv[lane + 128]  = r2;
    swv[lane + 192]  = r3;
    swv[lane + 256]  = r4;
    swv[lane + 320]  = r5;
    swv[lane + 384]  = r6;
    if (lane < 32) swv[lane + 448] = r7;

    const float m = (u8 ? (m_u8 != 0) : (m_i32 != 0)) ? 1.0f : 0.0f;

    // ---- per-cell compute (pred from LDS, tc from registers) ----
    float p[30];
    {
        const float2* pp = reinterpret_cast<const float2*>(spv[wid] + lane * 30);
        #pragma unroll
        for (int k = 0; k < 15; ++k) { float2 v = pp[k]; p[2*k] = v.x; p[2*k+1] = v.y; }
    }
    const float c[20] = {rc0.x, rc0.y, rc0.z, rc0.w, rc1.x, rc1.y, rc1.z, rc1.w,
                         rc2.x, rc2.y, rc2.z, rc2.w, rc3.x, rc3.y, rc3.z, rc3.w,
                         rc4.x, rc4.y, rc4.z, rc4.w};

    float clsv = 0.0f;
    #pragma unroll
    for (int k = 0; k < 20; ++k) { float d = p[10 + k] - c[k]; clsv = fmaf(d, d, clsv); }
    float cls = m * clsv;

    float noobj = (1.0f - m) * (p[4] * p[4] + p[9] * p[9]);

    const float invS = 1.0f / 14.0f;
    float tx0 = t4.x * invS - 0.5f * t4.z, ty0 = t4.y * invS - 0.5f * t4.w;
    float tx1 = t4.x * invS + 0.5f * t4.z, ty1 = t4.y * invS + 0.5f * t4.w;

    float a1x0 = p[0] * invS - 0.5f * p[2], a1y0 = p[1] * invS - 0.5f * p[3];
    float a1x1 = p[0] * invS + 0.5f * p[2], a1y1 = p[1] * invS + 0.5f * p[3];
    float a2x0 = p[5] * invS - 0.5f * p[7], a2y0 = p[6] * invS - 0.5f * p[8];
    float a2x1 = p[5] * invS + 0.5f * p[7], a2y1 = p[6] * invS + 0.5f * p[8];

    float iou1 = iou_xyxy(tx0, ty0, tx1, ty1, a1x0, a1y0, a1x1, a1y1);
    float iou2 = iou_xyxy(tx0, ty0, tx1, ty1, a2x0, a2y0, a2x1, a2y1);

    bool  use1 = iou1 > iou2;
    float biou = use1 ? iou1 : iou2;
    float bx = use1 ? p[0] : p[5];
    float by = use1 ? p[1] : p[6];
    float bw = use1 ? p[2] : p[7];
    float bh = use1 ? p[3] : p[8];
    float bc = use1 ? p[4] : p[9];

    float dx = bx - t4.x, dy = by - t4.y;
    float sw = sqrtf(bw) - sqrtf(t4.z);
    float sh = sqrtf(bh) - sqrtf(t4.w);
    float reg  = m * (dx * dx + dy * dy + sw * sw + sh * sh);
    float dc = bc - biou;
    float cont = m * dc * dc;

    // ---- wave (64-lane) reduction ----
    #pragma unroll
    for (int off = 32; off > 0; off >>= 1) {
        reg   += __shfl_down(reg,   off);
        cont  += __shfl_down(cont,  off);
        noobj += __shfl_down(noobj, off);
        cls   += __shfl_down(cls,   off);
    }

    if (lane == 0) {
        sred[wid][0] = reg; sred[wid][1] = cont;
        sred[wid][2] = noobj; sred[wid][3] = cls;
    }
    __syncthreads();                 // the only block-wide barrier
    if (tid == 0) {
        float r = 0, co = 0, no = 0, cl = 0;
        #pragma unroll
        for (int w = 0; w < 4; ++w) {
            r += sred[w][0]; co += sred[w][1]; no += sred[w][2]; cl += sred[w][3];
        }
        if (partials) {
            partials[blockIdx.x] = make_float4(r, co, no, cl);
        } else {
            atomicAdd(&out[0], 5.0f * r + co + 0.5f * no + cl);
            atomicAdd(&out[1], r);
            atomicAdd(&out[2], co);
            atomicAdd(&out[3], no);
            atomicAdd(&out[4], cl);
        }
    }
}

__global__ __launch_bounds__(256) void yolo_reduce(
    const float4* __restrict__ partials, float* __restrict__ out)
{
    const int tid = threadIdx.x;
    float r = 0, co = 0, no = 0, cl = 0;
    for (int i = tid; i < NBLK; i += 256) {
        float4 v = partials[i];
        r += v.x; co += v.y; no += v.z; cl += v.w;
    }
    #pragma unroll
    for (int off = 32; off > 0; off >>= 1) {
        r  += __shfl_down(r,  off);
        co += __shfl_down(co, off);
        no += __shfl_down(no, off);
        cl += __shfl_down(cl, off);
    }
    __shared__ float sred[4][4];
    const int wid  = tid >> 6;
    const int lane = tid & 63;
    if (lane == 0) { sred[wid][0] = r; sred[wid][1] = co; sred[wid][2] = no; sred[wid][3] = cl; }
    __syncthreads();
    if (tid == 0) {
        float R = 0, CO = 0, NO = 0, CL = 0;
        #pragma unroll
        for (int w = 0; w < 4; ++w) {
            R += sred[w][0]; CO += sred[w][1]; NO += sred[w][2]; CL += sred[w][3];
        }
        out[0] = 5.0f * R + CO + 0.5f * NO + CL;
        out[1] = R;
        out[2] = CO;
        out[3] = NO;
        out[4] = CL;
    }
}

extern "C" void kernel_launch(void* const* d_in, const int* in_sizes, int n_in,
                              void* d_out, int out_size, void* d_ws, size_t ws_size,
                              hipStream_t stream) {
    const float* pred         = (const float*)d_in[0];
    const float* tboxes       = (const float*)d_in[1];
    const float* tcls         = (const float*)d_in[2];
    const unsigned char* mask = (const unsigned char*)d_in[3];
    float* out = (float*)d_out;

    const bool two_stage = (ws_size >= (size_t)NBLK * sizeof(float4));
    float4* partials = two_stage ? (float4*)d_ws : nullptr;

    if (!two_stage) hipMemsetAsync(out, 0, 5 * sizeof(float), stream);

    yolo_main<<<NBLK, 256, 0, stream>>>(pred, tboxes, tcls, mask, partials, out);
    if (two_stage) yolo_reduce<<<1, 256, 0, stream>>>(partials, out);
}